// Round 13
// baseline (103.549 us; speedup 1.0000x reference)
//
#include <hip/hip_runtime.h>
#include <hip/hip_fp16.h>

namespace {
constexpr int kB = 2, kH = 16, kS = 2048, kD = 64, kBH = kB * kH;
constexpr int BQ = 128, BKV = 64;
constexpr int NQT = kS / BQ;   // 16

typedef _Float16 f16x8 __attribute__((ext_vector_type(8)));
typedef _Float16 f16x4 __attribute__((ext_vector_type(4)));
typedef __fp16 fp16x2 __attribute__((ext_vector_type(2)));
typedef float f32x16 __attribute__((ext_vector_type(16)));
typedef unsigned int u32;

// Q prescale: 1/sqrt(64) * log2(e) -> softmax done in exp2 domain.
constexpr float kQScale = 0.125f * 1.4426950408889634f;

// Packed LDS tile: 64 logical rows x 64 f16 -> 32 prows x 128 halfwords.
__device__ __forceinline__ int paddr(int row, int col) {
  const int prow = row >> 1;
  return prow * 128 + ((((row & 1) << 6) | col) ^ ((prow & 15) << 3));
}

__device__ __forceinline__ u32 pkrtz(float a, float b) {
  union { fp16x2 h; u32 u; } c;
  c.h = __builtin_amdgcn_cvt_pkrtz(a, b);
  return c.u;
}

// ---- preprocess 1: per-batch mask scan -> compaction index + NT(+even) + Nv
__global__ __launch_bounds__(256) void scan_kernel(const int* __restrict__ M,
                                                   int* __restrict__ Idx,
                                                   int* __restrict__ NTarr,
                                                   int* __restrict__ Nvarr) {
  const int b = blockIdx.x;
  const int tid = threadIdx.x;
  __shared__ int part[256];
  __shared__ int nvs;
  int m[8], sum = 0;
#pragma unroll
  for (int i = 0; i < 8; ++i) {
    m[i] = M[b * kS + tid * 8 + i];
    sum += m[i] ? 1 : 0;
  }
  part[tid] = sum;
  __syncthreads();
  for (int off = 1; off < 256; off <<= 1) {
    int v = (tid >= off) ? part[tid - off] : 0;
    __syncthreads();
    part[tid] += v;
    __syncthreads();
  }
  int run = part[tid] - sum;  // exclusive prefix
#pragma unroll
  for (int i = 0; i < 8; ++i)
    if (m[i]) Idx[b * kS + run++] = tid * 8 + i;
  if (tid == 255) nvs = part[255];
  __syncthreads();
  const int Nv = nvs;
  int NT = (Nv + 63) >> 6;
  if (NT == 0) NT = 1;
  NT += (NT & 1);  // even, so the two wave-halves split tiles evenly (<=32)
  const int pad = NT * 64;
  for (int j = Nv + tid; j < pad; j += 256) Idx[b * kS + j] = 0;
  if (tid == 0) { NTarr[b] = NT; Nvarr[b] = Nv; }
}

// ---- preprocess 2 (fused): gather K -> f16 [bh][j][d] and V -> f16^T
// [bh][d][j], one block per (bh, key-tile). ----
__global__ __launch_bounds__(256) void gather_kv_kernel(
    const float* __restrict__ K, const float* __restrict__ V,
    const int* __restrict__ Idx, const int* __restrict__ NTarr,
    _Float16* __restrict__ Kc, _Float16* __restrict__ Vtc) {
  __shared__ _Float16 Vl[64 * 68];
  __shared__ int ridx[64];
  const int tid = threadIdx.x;
  const int bh = blockIdx.x >> 5;
  const int jt = blockIdx.x & 31;
  const int b = bh >> 4;
  if (jt >= NTarr[b]) return;
  if (tid < 64) ridx[tid] = Idx[b * kS + jt * 64 + tid];
  __syncthreads();

  const float* kbase = K + (size_t)bh * kS * kD;
  _Float16* kout = Kc + ((size_t)bh * kS + jt * 64) * kD;
#pragma unroll
  for (int it = 0; it < 2; ++it) {
    const int e = tid + 256 * it;
    const int row = e >> 3, d0 = (e & 7) * 8;
    const float* p = kbase + (size_t)ridx[row] * kD + d0;
    float4 x = *(const float4*)p;
    float4 y = *(const float4*)(p + 4);
    f16x8 o;
    o[0] = (_Float16)x.x; o[1] = (_Float16)x.y; o[2] = (_Float16)x.z; o[3] = (_Float16)x.w;
    o[4] = (_Float16)y.x; o[5] = (_Float16)y.y; o[6] = (_Float16)y.z; o[7] = (_Float16)y.w;
    *(f16x8*)(kout + (size_t)row * kD + d0) = o;
  }

  const float* vb = V + (size_t)bh * kS * kD;
#pragma unroll
  for (int i = 0; i < 4; ++i) {
    int off = (tid + 256 * i) * 4;
    int r = off >> 6, c = off & 63;
    float4 x = *(const float4*)(vb + (size_t)ridx[r] * kD + c);
    Vl[(c + 0) * 68 + r] = (_Float16)x.x;
    Vl[(c + 1) * 68 + r] = (_Float16)x.y;
    Vl[(c + 2) * 68 + r] = (_Float16)x.z;
    Vl[(c + 3) * 68 + r] = (_Float16)x.w;
  }
  __syncthreads();
  const int d = tid >> 2, c0 = (tid & 3) * 16;
  _Float16* op = Vtc + ((size_t)bh * kD + d) * kS + jt * 64 + c0;
#pragma unroll
  for (int j = 0; j < 4; ++j)
    *(f16x4*)(op + 4 * j) = *(const f16x4*)(Vl + d * 68 + c0 + 4 * j);
}

// ------- main: 8-wave block, in-block split-K x2 over compacted keys -------
// half 0 (waves 0-3): KV tiles [0,NT/2); half 1 (waves 4-7): [NT/2,NT).
// Both halves cover the same 128 q-rows. K staged in per-half LDS dbuf;
// V loaded direct global->reg (L2-resident; ~1 tile of slack to PV).
// Final merge (max-rebase) done in LDS; no merge kernel.
__global__ __launch_bounds__(512, 4) void fattn8(
    const _Float16* __restrict__ Kc, const _Float16* __restrict__ Vtc,
    const float* __restrict__ Q, const int* __restrict__ NTarr,
    const int* __restrict__ Nvarr, float* __restrict__ O) {
  // [0,16K): half0 K dbuf | [16K,32K): half1 K dbuf
  // [32K,64K): merge O1 f32[128][64] | [64K,65K): ml1 f32x2[128]
  // Os f32[64][68] overlays [0,17408) in the epilogue.
  __shared__ __align__(16) char smem[66560];

  const int tid = threadIdx.x;
  const int lane = tid & 63;
  const int q = lane & 31;   // qrow within wave tile
  const int h = lane >> 5;   // half-of-wave 0/1
  const int half = tid >> 8; // KV half 0/1
  const int ptid = tid & 255;
  const int hw = ptid >> 6;  // wave within half -> q-row group

  // XCD-aware bijective swizzle (gridDim = 512, %8 == 0).
  const int bid = blockIdx.x;
  const int cpx = gridDim.x >> 3;
  const int sbid = (bid & 7) * cpx + (bid >> 3);
  const int bh = sbid >> 4;
  const int qt = sbid & 15;
  const int q0 = qt * BQ;
  const int b = bh >> 4;  // H=16
  const int NT = NTarr[b];   // even
  const int Nv = Nvarr[b];
  const int NTh = NT >> 1;
  const int g0 = half * NTh;

  _Float16* Kl = (_Float16*)(smem + half * 16384);  // [2][4096]

  // Q fragments (B-operand), pre-scaled into exp2 domain.
  f16x8 qf[4];
  {
    const float* qp = Q + ((size_t)bh * kS + q0 + hw * 32 + q) * kD;
#pragma unroll
    for (int dc = 0; dc < 4; ++dc) {
      const float* p = qp + dc * 16 + h * 8;
      float4 x = *(const float4*)p;
      float4 y = *(const float4*)(p + 4);
      f16x8 a;
      a[0] = (_Float16)(x.x * kQScale); a[1] = (_Float16)(x.y * kQScale);
      a[2] = (_Float16)(x.z * kQScale); a[3] = (_Float16)(x.w * kQScale);
      a[4] = (_Float16)(y.x * kQScale); a[5] = (_Float16)(y.y * kQScale);
      a[6] = (_Float16)(y.z * kQScale); a[7] = (_Float16)(y.w * kQScale);
      qf[dc] = a;
    }
  }

  f32x16 oa[2];
#pragma unroll
  for (int i = 0; i < 16; ++i) { oa[0][i] = 0.f; oa[1][i] = 0.f; }
  float m_run = -30.f, l_run = 0.f;

  const _Float16* kb = Kc + (size_t)bh * kS * kD;
  const _Float16* vb = Vtc + (size_t)bh * kD * kS;
  const _Float16* vrow0 = vb + (size_t)q * kS + h * 8;         // d = q
  const _Float16* vrow1 = vb + (size_t)(q + 32) * kS + h * 8;  // d = q+32

  // K staging geometry (256 threads per half -> 64x64 tile)
  const int sr = ptid >> 2, sc = (ptid & 3) * 16;
  const int a0 = paddr(sr, sc), a1 = paddr(sr, sc + 8);

  f16x8 nk0, nk1, vr[8];

  // prologue: stage this half's tile 0
  nk0 = *(const f16x8*)(kb + (size_t)(g0 * 64 + sr) * kD + sc);
  nk1 = *(const f16x8*)(kb + (size_t)(g0 * 64 + sr) * kD + sc + 8);
  *(f16x8*)(Kl + a0) = nk0;
  *(f16x8*)(Kl + a1) = nk1;
  __syncthreads();

  int cur = 0;
  for (int i = 0; i < NTh; ++i) {
    const int g = g0 + i;
    // ---- V direct loads: issued now, consumed at PV (~1 tile of slack) ----
#pragma unroll
    for (int kk = 0; kk < 4; ++kk) {
      vr[kk] = *(const f16x8*)(vrow0 + g * 64 + kk * 16);
      vr[4 + kk] = *(const f16x8*)(vrow1 + g * 64 + kk * 16);
    }
    const bool pf = (i + 1 < NTh);
    if (pf) {  // T14: next K tile global->reg, in flight across this iter
      const int n0 = (g + 1) * 64;
      nk0 = *(const f16x8*)(kb + (size_t)(n0 + sr) * kD + sc);
      nk1 = *(const f16x8*)(kb + (size_t)(n0 + sr) * kD + sc + 8);
    }

    const _Float16* kd = Kl + cur * 4096;

    // ---- QK^T (swapped), zero C-init ----
    // s[mt][r] has key = g*64 + mt*32 + 8*(r>>2) + 4*h + (r&3), qrow = q
    f32x16 s[2];
    __builtin_amdgcn_s_setprio(1);
#pragma unroll
    for (int mt = 0; mt < 2; ++mt) {
      f32x16 z;
#pragma unroll
      for (int i2 = 0; i2 < 16; ++i2) z[i2] = 0.f;
#pragma unroll
      for (int dc = 0; dc < 4; ++dc) {
        f16x8 kf = *(const f16x8*)(kd + paddr(mt * 32 + q, dc * 16 + h * 8));
        z = __builtin_amdgcn_mfma_f32_32x32x16_f16(kf, qf[dc], z, 0, 0, 0);
      }
      s[mt] = z;
    }
    __builtin_amdgcn_s_setprio(0);

    // ---- pad-mask (only tiles overlapping [Nv, NT*64)): pure VALU ----
    if ((g + 1) * 64 > Nv) {
      const int kbase = g * 64 + 4 * h;
#pragma unroll
      for (int mt = 0; mt < 2; ++mt)
#pragma unroll
        for (int r = 0; r < 16; ++r) {
          const int key = kbase + mt * 32 + 8 * (r >> 2) + (r & 3);
          if (key >= Nv) s[mt][r] = -1e30f;
        }
    }

    // ---- tile max (tree) + cross-half combine ----
    float tm[16];
#pragma unroll
    for (int i2 = 0; i2 < 16; ++i2) tm[i2] = fmaxf(s[0][i2], s[1][i2]);
#pragma unroll
    for (int st = 8; st > 0; st >>= 1)
#pragma unroll
      for (int i2 = 0; i2 < st; ++i2) tm[i2] = fmaxf(tm[i2], tm[i2 + st]);
    const float mx = fmaxf(tm[0], __shfl_xor(tm[0], 32));

    // ---- defer-max (T13) ----
    if (__any(mx > m_run + 8.f)) {
      const float mnew = fmaxf(m_run, mx);
      const float corr = __builtin_amdgcn_exp2f(m_run - mnew);
      m_run = mnew;
      l_run *= corr;
#pragma unroll
      for (int mt = 0; mt < 2; ++mt)
#pragma unroll
        for (int r = 0; r < 16; ++r) oa[mt][r] *= corr;
    }
    const float negm = -m_run;

    // ---- p = exp2(s - m); tree sum ----
#pragma unroll
    for (int mt = 0; mt < 2; ++mt)
#pragma unroll
      for (int r = 0; r < 16; ++r)
        s[mt][r] = __builtin_amdgcn_exp2f(s[mt][r] + negm);
    float tsum[16];
#pragma unroll
    for (int i2 = 0; i2 < 16; ++i2) tsum[i2] = s[0][i2] + s[1][i2];
#pragma unroll
    for (int st = 8; st > 0; st >>= 1)
#pragma unroll
      for (int i2 = 0; i2 < st; ++i2) tsum[i2] += tsum[i2 + st];
    l_run += tsum[0] + __shfl_xor(tsum[0], 32);

    // ---- pack P to f16 pairs ----
    u32 pkA[2][4], pkB[2][4];
#pragma unroll
    for (int mt = 0; mt < 2; ++mt)
#pragma unroll
      for (int g2 = 0; g2 < 4; ++g2) {
        pkA[mt][g2] = pkrtz(s[mt][4 * g2 + 0], s[mt][4 * g2 + 1]);
        pkB[mt][g2] = pkrtz(s[mt][4 * g2 + 2], s[mt][4 * g2 + 3]);
      }

    // ---- PV (swapped): oa[md] += V^T * P ; V from registers ----
    __builtin_amdgcn_s_setprio(1);
#pragma unroll
    for (int kk = 0; kk < 4; ++kk) {
      const int e = kk & 1, mt = kk >> 1;
      u32 crossA = __shfl_xor(h ? pkA[mt][2 * e] : pkA[mt][2 * e + 1], 32);
      u32 crossB = __shfl_xor(h ? pkB[mt][2 * e] : pkB[mt][2 * e + 1], 32);
      union { u32 u[4]; f16x8 v; } pb;
      pb.u[0] = h ? crossA : pkA[mt][2 * e];
      pb.u[1] = h ? crossB : pkB[mt][2 * e];
      pb.u[2] = h ? pkA[mt][2 * e + 1] : crossA;
      pb.u[3] = h ? pkB[mt][2 * e + 1] : crossB;
#pragma unroll
      for (int md = 0; md < 2; ++md)
        oa[md] = __builtin_amdgcn_mfma_f32_32x32x16_f16(vr[md * 4 + kk], pb.v,
                                                        oa[md], 0, 0, 0);
    }
    __builtin_amdgcn_s_setprio(0);

    // ---- write prefetched K tile into the other buffer ----
    if (pf) {
      _Float16* kd2 = Kl + (cur ^ 1) * 4096;
      *(f16x8*)(kd2 + a0) = nk0;
      *(f16x8*)(kd2 + a1) = nk1;
    }
    __syncthreads();
    cur ^= 1;
  }

  // ---- merge: half1 publishes unnormalized O + (m,l); half0 combines ----
  float* O1 = (float*)(smem + 32768);   // [128 rows][64 d]
  float* ml1 = (float*)(smem + 65536);  // float2 per row
  if (half == 1) {
#pragma unroll
    for (int mt = 0; mt < 2; ++mt)
#pragma unroll
      for (int r = 0; r < 16; ++r) {
        const int d = mt * 32 + (r & 3) + 8 * (r >> 2) + 4 * h;
        O1[(hw * 32 + q) * 64 + d] = oa[mt][r];
      }
    if (h == 0)
      ((float2*)ml1)[hw * 32 + q] = make_float2(m_run, l_run);
  }
  __syncthreads();
  float w0 = 0.f, w1 = 0.f;
  if (half == 0) {
    const float2 m1 = ((const float2*)ml1)[hw * 32 + q];
    const float mm = fmaxf(m_run, m1.x);
    w0 = __builtin_amdgcn_exp2f(m_run - mm);
    w1 = __builtin_amdgcn_exp2f(m1.x - mm);
    const float inv = 1.f / (l_run * w0 + m1.y * w1);
    w0 *= inv;
    w1 *= inv;
  }
  float* Os = (float*)smem;  // [64][68] overlay, safe after the K-loop
#pragma unroll
  for (int ph = 0; ph < 2; ++ph) {
    __syncthreads();
    if (half == 0 && (hw >> 1) == ph) {
#pragma unroll
      for (int mt = 0; mt < 2; ++mt)
#pragma unroll
        for (int r = 0; r < 16; ++r) {
          const int d = mt * 32 + (r & 3) + 8 * (r >> 2) + 4 * h;
          const int gqr = hw * 32 + q;           // global q-row in tile
          Os[((hw & 1) * 32 + q) * 68 + d] = oa[mt][r] * w0 + O1[gqr * 64 + d] * w1;
        }
    }
    __syncthreads();
    {
      const int row = tid >> 3, c0 = (tid & 7) * 8;
      float* op = O + ((size_t)bh * kS + q0 + ph * 64 + row) * kD + c0;
      const float* sp = Os + row * 68 + c0;
      *(float4*)op = *(const float4*)sp;
      *(float4*)(op + 4) = *(const float4*)(sp + 4);
    }
  }
}

// ---------------- fallback (round-1 kernel) if ws is too small -------------
__device__ __forceinline__ int swz(int row, int colh) {
  return row * 64 + (colh ^ ((row & 7) << 3));
}

__global__ __launch_bounds__(256, 4) void fattn_fallback(
    const float* __restrict__ Q, const float* __restrict__ K,
    const float* __restrict__ V, const int* __restrict__ M,
    float* __restrict__ O) {
  __shared__ __align__(16) _Float16 Kl[64 * 64];
  __shared__ __align__(16) _Float16 Vtl[64 * 64];
  __shared__ __align__(16) _Float16 Pl[64 * 64];
  __shared__ float mbl[64];

  const int tid = threadIdx.x;
  const int lane = tid & 63;
  const int w = tid >> 6;
  const int lr = lane & 15;
  const int hg = lane >> 4;
  const int NQT1 = kS / 64;
  const int bh = blockIdx.x / NQT1;
  const int qt = blockIdx.x % NQT1;
  const int b = bh / kH;
  const int q0 = qt * 64;

  f16x8 aq[2];
  {
    const int row = q0 + w * 16 + lr;
    const float* qp = Q + ((size_t)bh * kS + row) * kD;
#pragma unroll
    for (int kf = 0; kf < 2; ++kf) {
      const float* p = qp + kf * 32 + hg * 8;
      float4 x = *(const float4*)(p);
      float4 y = *(const float4*)(p + 4);
      f16x8 a;
      a[0] = (_Float16)(x.x * 0.125f); a[1] = (_Float16)(x.y * 0.125f);
      a[2] = (_Float16)(x.z * 0.125f); a[3] = (_Float16)(x.w * 0.125f);
      a[4] = (_Float16)(y.x * 0.125f); a[5] = (_Float16)(y.y * 0.125f);
      a[6] = (_Float16)(y.z * 0.125f); a[7] = (_Float16)(y.w * 0.125f);
      aq[kf] = a;
    }
  }

  typedef float f32x4 __attribute__((ext_vector_type(4)));
  f32x4 oacc[4];
#pragma unroll
  for (int c = 0; c < 4; ++c) { oacc[c][0]=0.f; oacc[c][1]=0.f; oacc[c][2]=0.f; oacc[c][3]=0.f; }
  float m_run[4], l_run[4];
#pragma unroll
  for (int r = 0; r < 4; ++r) { m_run[r] = -1e30f; l_run[r] = 0.f; }

  const float* kb = K + (size_t)bh * kS * kD;
  const float* vb = V + (size_t)bh * kS * kD;
  const int* mbp = M + b * kS;

  for (int t0 = 0; t0 < kS; t0 += 64) {
    __syncthreads();
#pragma unroll
    for (int i = 0; i < 4; ++i) {
      const int off = (tid + 256 * i) * 4;
      const int row = off >> 6;
      const int col = off & 63;
      float4 kx = *(const float4*)(kb + (size_t)(t0 + row) * kD + col);
      f16x4 hk;
      hk[0] = (_Float16)kx.x; hk[1] = (_Float16)kx.y;
      hk[2] = (_Float16)kx.z; hk[3] = (_Float16)kx.w;
      *(f16x4*)(Kl + swz(row, col)) = hk;
      float4 vx = *(const float4*)(vb + (size_t)(t0 + row) * kD + col);
      Vtl[swz(col + 0, row)] = (_Float16)vx.x;
      Vtl[swz(col + 1, row)] = (_Float16)vx.y;
      Vtl[swz(col + 2, row)] = (_Float16)vx.z;
      Vtl[swz(col + 3, row)] = (_Float16)vx.w;
    }
    if (tid < 64) mbl[tid] = mbp[t0 + tid] ? 0.f : -1e30f;
    __syncthreads();

    f32x4 s[4];
#pragma unroll
    for (int c = 0; c < 4; ++c) {
      f32x4 z; z[0]=0.f; z[1]=0.f; z[2]=0.f; z[3]=0.f;
#pragma unroll
      for (int kf = 0; kf < 2; ++kf) {
        f16x8 bk = *(const f16x8*)(Kl + swz(c * 16 + lr, kf * 32 + hg * 8));
        z = __builtin_amdgcn_mfma_f32_16x16x32_f16(aq[kf], bk, z, 0, 0, 0);
      }
      const float mval = mbl[c * 16 + lr];
#pragma unroll
      for (int r = 0; r < 4; ++r) z[r] += mval;
      s[c] = z;
    }

    float tmax[4];
#pragma unroll
    for (int r = 0; r < 4; ++r)
      tmax[r] = fmaxf(fmaxf(s[0][r], s[1][r]), fmaxf(s[2][r], s[3][r]));
#pragma unroll
    for (int off = 1; off < 16; off <<= 1)
#pragma unroll
      for (int r = 0; r < 4; ++r) tmax[r] = fmaxf(tmax[r], __shfl_xor(tmax[r], off));

    float mnew[4], corr[4], tsum[4];
#pragma unroll
    for (int r = 0; r < 4; ++r) {
      mnew[r] = fmaxf(m_run[r], tmax[r]);
      corr[r] = __expf(m_run[r] - mnew[r]);
      m_run[r] = mnew[r];
      tsum[r] = 0.f;
    }
#pragma unroll
    for (int c = 0; c < 4; ++c)
#pragma unroll
      for (int r = 0; r < 4; ++r) {
        const float p = __expf(s[c][r] - mnew[r]);
        tsum[r] += p;
        Pl[swz(w * 16 + hg * 4 + r, c * 16 + lr)] = (_Float16)p;
      }
#pragma unroll
    for (int off = 1; off < 16; off <<= 1)
#pragma unroll
      for (int r = 0; r < 4; ++r) tsum[r] += __shfl_xor(tsum[r], off);
#pragma unroll
    for (int r = 0; r < 4; ++r) l_run[r] = l_run[r] * corr[r] + tsum[r];
#pragma unroll
    for (int c = 0; c < 4; ++c)
#pragma unroll
      for (int r = 0; r < 4; ++r) oacc[c][r] *= corr[r];

#pragma unroll
    for (int kf = 0; kf < 2; ++kf) {
      f16x8 pa = *(const f16x8*)(Pl + swz(w * 16 + lr, kf * 32 + hg * 8));
#pragma unroll
      for (int cd = 0; cd < 4; ++cd) {
        f16x8 vbf = *(const f16x8*)(Vtl + swz(cd * 16 + lr, kf * 32 + hg * 8));
        oacc[cd] = __builtin_amdgcn_mfma_f32_16x16x32_f16(pa, vbf, oacc[cd], 0, 0, 0);
      }
    }
  }

#pragma unroll
  for (int r = 0; r < 4; ++r) {
    const float inv = 1.f / l_run[r];
    const int row = q0 + w * 16 + hg * 4 + r;
    float* op = O + ((size_t)bh * kS + row) * kD;
#pragma unroll
    for (int cd = 0; cd < 4; ++cd) op[cd * 16 + lr] = oacc[cd][r] * inv;
  }
}
}  // namespace

extern "C" void kernel_launch(void* const* d_in, const int* in_sizes, int n_in,
                              void* d_out, int out_size, void* d_ws, size_t ws_size,
                              hipStream_t stream) {
  (void)in_sizes; (void)n_in; (void)out_size;
  const float* q = (const float*)d_in[0];
  const float* k = (const float*)d_in[1];
  const float* v = (const float*)d_in[2];
  const int* m = (const int*)d_in[3];
  float* o = (float*)d_out;

  const size_t elems = (size_t)kBH * kS * kD;  // 4.19M
  const size_t need = 2 * elems * sizeof(_Float16)    // Kc + Vtc
                    + (size_t)kB * kS * sizeof(int)   // Idx
                    + 512;                            // NTarr + Nvarr

  if (ws_size >= need) {
    _Float16* Kc = (_Float16*)d_ws;
    _Float16* Vtc = Kc + elems;
    int* Idx = (int*)(Vtc + elems);
    int* NTarr = Idx + (size_t)kB * kS;
    int* Nvarr = NTarr + 64;
    hipLaunchKernelGGL(scan_kernel, dim3(kB), dim3(256), 0, stream, m, Idx, NTarr, Nvarr);
    hipLaunchKernelGGL(gather_kv_kernel, dim3(kBH * (kS / 64)), dim3(256), 0, stream,
                       k, v, Idx, NTarr, Kc, Vtc);
    hipLaunchKernelGGL(fattn8, dim3(kBH * NQT), dim3(512), 0, stream,
                       Kc, Vtc, q, NTarr, Nvarr, o);
  } else {
    hipLaunchKernelGGL(fattn_fallback, dim3(kBH * (kS / 64)), dim3(256), 0, stream,
                       q, k, v, m, o);
  }
}

// Round 14
// 58.291 us; speedup vs baseline: 1.7764x; 1.7764x over previous
//
#include <hip/hip_runtime.h>
#include <hip/hip_fp16.h>

namespace {
constexpr int kB = 2, kH = 16, kS = 2048, kD = 64, kBH = kB * kH;
constexpr int BQ = 128, BKV = 64;
constexpr int NQT = kS / BQ;   // 16

typedef _Float16 f16x8 __attribute__((ext_vector_type(8)));
typedef _Float16 f16x4 __attribute__((ext_vector_type(4)));
typedef __fp16 fp16x2 __attribute__((ext_vector_type(2)));
typedef float f32x16 __attribute__((ext_vector_type(16)));
typedef unsigned int u32;

// Q prescale: 1/sqrt(64) * log2(e) -> softmax done in exp2 domain.
constexpr float kQScale = 0.125f * 1.4426950408889634f;

// Packed LDS tile: 64 logical rows x 64 f16 -> 32 prows x 128 halfwords.
__device__ __forceinline__ int paddr(int row, int col) {
  const int prow = row >> 1;
  return prow * 128 + ((((row & 1) << 6) | col) ^ ((prow & 15) << 3));
}

__device__ __forceinline__ u32 pkrtz(float a, float b) {
  union { fp16x2 h; u32 u; } c;
  c.h = __builtin_amdgcn_cvt_pkrtz(a, b);
  return c.u;
}

// ---- preprocess 1: per-batch mask scan -> compaction index + NT(+even) + Nv
__global__ __launch_bounds__(256) void scan_kernel(const int* __restrict__ M,
                                                   int* __restrict__ Idx,
                                                   int* __restrict__ NTarr,
                                                   int* __restrict__ Nvarr) {
  const int b = blockIdx.x;
  const int tid = threadIdx.x;
  __shared__ int part[256];
  __shared__ int nvs;
  int m[8], sum = 0;
#pragma unroll
  for (int i = 0; i < 8; ++i) {
    m[i] = M[b * kS + tid * 8 + i];
    sum += m[i] ? 1 : 0;
  }
  part[tid] = sum;
  __syncthreads();
  for (int off = 1; off < 256; off <<= 1) {
    int v = (tid >= off) ? part[tid - off] : 0;
    __syncthreads();
    part[tid] += v;
    __syncthreads();
  }
  int run = part[tid] - sum;  // exclusive prefix
#pragma unroll
  for (int i = 0; i < 8; ++i)
    if (m[i]) Idx[b * kS + run++] = tid * 8 + i;
  if (tid == 255) nvs = part[255];
  __syncthreads();
  const int Nv = nvs;
  int NT = (Nv + 63) >> 6;
  if (NT == 0) NT = 1;
  NT += (NT & 1);  // even, so the two wave-halves split tiles evenly (<=32)
  const int pad = NT * 64;
  for (int j = Nv + tid; j < pad; j += 256) Idx[b * kS + j] = 0;
  if (tid == 0) { NTarr[b] = NT; Nvarr[b] = Nv; }
}

// ---- preprocess 2 (fused): gather K -> f16 [bh][j][d] and V -> f16^T
// [bh][d][j], one block per (bh, key-tile). ----
__global__ __launch_bounds__(256) void gather_kv_kernel(
    const float* __restrict__ K, const float* __restrict__ V,
    const int* __restrict__ Idx, const int* __restrict__ NTarr,
    _Float16* __restrict__ Kc, _Float16* __restrict__ Vtc) {
  __shared__ _Float16 Vl[64 * 68];
  __shared__ int ridx[64];
  const int tid = threadIdx.x;
  const int bh = blockIdx.x >> 5;
  const int jt = blockIdx.x & 31;
  const int b = bh >> 4;
  if (jt >= NTarr[b]) return;
  if (tid < 64) ridx[tid] = Idx[b * kS + jt * 64 + tid];
  __syncthreads();

  const float* kbase = K + (size_t)bh * kS * kD;
  _Float16* kout = Kc + ((size_t)bh * kS + jt * 64) * kD;
#pragma unroll
  for (int it = 0; it < 2; ++it) {
    const int e = tid + 256 * it;
    const int row = e >> 3, d0 = (e & 7) * 8;
    const float* p = kbase + (size_t)ridx[row] * kD + d0;
    float4 x = *(const float4*)p;
    float4 y = *(const float4*)(p + 4);
    f16x8 o;
    o[0] = (_Float16)x.x; o[1] = (_Float16)x.y; o[2] = (_Float16)x.z; o[3] = (_Float16)x.w;
    o[4] = (_Float16)y.x; o[5] = (_Float16)y.y; o[6] = (_Float16)y.z; o[7] = (_Float16)y.w;
    *(f16x8*)(kout + (size_t)row * kD + d0) = o;
  }

  const float* vb = V + (size_t)bh * kS * kD;
#pragma unroll
  for (int i = 0; i < 4; ++i) {
    int off = (tid + 256 * i) * 4;
    int r = off >> 6, c = off & 63;
    float4 x = *(const float4*)(vb + (size_t)ridx[r] * kD + c);
    Vl[(c + 0) * 68 + r] = (_Float16)x.x;
    Vl[(c + 1) * 68 + r] = (_Float16)x.y;
    Vl[(c + 2) * 68 + r] = (_Float16)x.z;
    Vl[(c + 3) * 68 + r] = (_Float16)x.w;
  }
  __syncthreads();
  const int d = tid >> 2, c0 = (tid & 3) * 16;
  _Float16* op = Vtc + ((size_t)bh * kD + d) * kS + jt * 64 + c0;
#pragma unroll
  for (int j = 0; j < 4; ++j)
    *(f16x4*)(op + 4 * j) = *(const f16x4*)(Vl + d * 68 + c0 + 4 * j);
}

// ------- main: 8-wave block, in-block split-K x2 over compacted keys -------
// half 0 (waves 0-3): KV tiles [0,NT/2); half 1 (waves 4-7): [NT/2,NT).
// Both halves cover the same 128 q-rows. K AND V staged in per-half LDS
// double-buffers (coalesced loads, R12's proven body). Merge in LDS
// (overlaying half1's staging after the final barrier); no merge kernel.
__global__ __launch_bounds__(512, 4) void fattn8(
    const _Float16* __restrict__ Kc, const _Float16* __restrict__ Vtc,
    const float* __restrict__ Q, const int* __restrict__ NTarr,
    const int* __restrict__ Nvarr, float* __restrict__ O) {
  // half0: K dbuf [0,16K) V dbuf [16K,32K) | half1: K [32K,48K) V [48K,64K)
  // ml1 [64K,65K). After the loop: O1 f32[128][64] overlays [32K,64K);
  // Os f32[64][68] overlays [0,17408).
  __shared__ __align__(16) char smem[66560];

  const int tid = threadIdx.x;
  const int lane = tid & 63;
  const int q = lane & 31;   // qrow within wave tile
  const int h = lane >> 5;   // half-of-wave 0/1
  const int half = tid >> 8; // KV half 0/1
  const int ptid = tid & 255;
  const int hw = ptid >> 6;  // wave within half -> q-row group

  // XCD-aware bijective swizzle (gridDim = 512, %8 == 0).
  const int bid = blockIdx.x;
  const int cpx = gridDim.x >> 3;
  const int sbid = (bid & 7) * cpx + (bid >> 3);
  const int bh = sbid >> 4;
  const int qt = sbid & 15;
  const int q0 = qt * BQ;
  const int b = bh >> 4;  // H=16
  const int NT = NTarr[b];   // even
  const int Nv = Nvarr[b];
  const int NTh = NT >> 1;
  const int g0 = half * NTh;

  _Float16* Kl = (_Float16*)(smem + half * 32768);          // [2][4096]
  _Float16* Vl = (_Float16*)(smem + half * 32768 + 16384);  // [2][4096]

  // Q fragments (B-operand), pre-scaled into exp2 domain.
  f16x8 qf[4];
  {
    const float* qp = Q + ((size_t)bh * kS + q0 + hw * 32 + q) * kD;
#pragma unroll
    for (int dc = 0; dc < 4; ++dc) {
      const float* p = qp + dc * 16 + h * 8;
      float4 x = *(const float4*)p;
      float4 y = *(const float4*)(p + 4);
      f16x8 a;
      a[0] = (_Float16)(x.x * kQScale); a[1] = (_Float16)(x.y * kQScale);
      a[2] = (_Float16)(x.z * kQScale); a[3] = (_Float16)(x.w * kQScale);
      a[4] = (_Float16)(y.x * kQScale); a[5] = (_Float16)(y.y * kQScale);
      a[6] = (_Float16)(y.z * kQScale); a[7] = (_Float16)(y.w * kQScale);
      qf[dc] = a;
    }
  }

  f32x16 oa[2];
#pragma unroll
  for (int i = 0; i < 16; ++i) { oa[0][i] = 0.f; oa[1][i] = 0.f; }
  float m_run = -30.f, l_run = 0.f;

  const _Float16* kb = Kc + (size_t)bh * kS * kD;
  const _Float16* vb = Vtc + (size_t)bh * kD * kS;

  // staging geometry (256 threads per half -> 64x64 tiles, coalesced)
  const int sr = ptid >> 2, sc = (ptid & 3) * 16;
  const int a0 = paddr(sr, sc), a1 = paddr(sr, sc + 8);

  f16x8 nk0, nk1, nv0, nv1;
  auto loadT = [&](int g) {
    const _Float16* kp = kb + (size_t)(g * 64 + sr) * kD + sc;
    const _Float16* vp = vb + (size_t)sr * kS + g * 64 + sc;
    nk0 = *(const f16x8*)(kp);
    nk1 = *(const f16x8*)(kp + 8);
    nv0 = *(const f16x8*)(vp);
    nv1 = *(const f16x8*)(vp + 8);
  };
  auto writeT = [&](int buf) {
    _Float16* kd = Kl + buf * 4096;
    _Float16* vd = Vl + buf * 4096;
    *(f16x8*)(kd + a0) = nk0; *(f16x8*)(kd + a1) = nk1;
    *(f16x8*)(vd + a0) = nv0; *(f16x8*)(vd + a1) = nv1;
  };

  // prologue: stage this half's tile 0
  loadT(g0);
  writeT(0);
  __syncthreads();

  int cur = 0;
  for (int i = 0; i < NTh; ++i) {
    const int g = g0 + i;
    const bool pf = (i + 1 < NTh);
    if (pf) loadT(g + 1);  // T14: next tile global->reg, in flight this iter

    const _Float16* kd = Kl + cur * 4096;
    const _Float16* vd = Vl + cur * 4096;

    // ---- QK^T (swapped), zero C-init ----
    // s[mt][r] has key = g*64 + mt*32 + 8*(r>>2) + 4*h + (r&3), qrow = q
    f32x16 s[2];
    __builtin_amdgcn_s_setprio(1);
#pragma unroll
    for (int mt = 0; mt < 2; ++mt) {
      f32x16 z;
#pragma unroll
      for (int i2 = 0; i2 < 16; ++i2) z[i2] = 0.f;
#pragma unroll
      for (int dc = 0; dc < 4; ++dc) {
        f16x8 kf = *(const f16x8*)(kd + paddr(mt * 32 + q, dc * 16 + h * 8));
        z = __builtin_amdgcn_mfma_f32_32x32x16_f16(kf, qf[dc], z, 0, 0, 0);
      }
      s[mt] = z;
    }
    __builtin_amdgcn_s_setprio(0);

    // ---- pad-mask (only tiles overlapping [Nv, ...)): pure VALU ----
    if ((g + 1) * 64 > Nv) {
      const int kbase = g * 64 + 4 * h;
#pragma unroll
      for (int mt = 0; mt < 2; ++mt)
#pragma unroll
        for (int r = 0; r < 16; ++r) {
          const int key = kbase + mt * 32 + 8 * (r >> 2) + (r & 3);
          if (key >= Nv) s[mt][r] = -1e30f;
        }
    }

    // ---- tile max (tree) + cross-half combine ----
    float tm[16];
#pragma unroll
    for (int i2 = 0; i2 < 16; ++i2) tm[i2] = fmaxf(s[0][i2], s[1][i2]);
#pragma unroll
    for (int st = 8; st > 0; st >>= 1)
#pragma unroll
      for (int i2 = 0; i2 < st; ++i2) tm[i2] = fmaxf(tm[i2], tm[i2 + st]);
    const float mx = fmaxf(tm[0], __shfl_xor(tm[0], 32));

    // ---- defer-max (T13) ----
    if (__any(mx > m_run + 8.f)) {
      const float mnew = fmaxf(m_run, mx);
      const float corr = __builtin_amdgcn_exp2f(m_run - mnew);
      m_run = mnew;
      l_run *= corr;
#pragma unroll
      for (int mt = 0; mt < 2; ++mt)
#pragma unroll
        for (int r = 0; r < 16; ++r) oa[mt][r] *= corr;
    }
    const float negm = -m_run;

    // ---- p = exp2(s - m); tree sum ----
#pragma unroll
    for (int mt = 0; mt < 2; ++mt)
#pragma unroll
      for (int r = 0; r < 16; ++r)
        s[mt][r] = __builtin_amdgcn_exp2f(s[mt][r] + negm);
    float tsum[16];
#pragma unroll
    for (int i2 = 0; i2 < 16; ++i2) tsum[i2] = s[0][i2] + s[1][i2];
#pragma unroll
    for (int st = 8; st > 0; st >>= 1)
#pragma unroll
      for (int i2 = 0; i2 < st; ++i2) tsum[i2] += tsum[i2 + st];
    l_run += tsum[0] + __shfl_xor(tsum[0], 32);

    // ---- pack P to f16 pairs ----
    u32 pkA[2][4], pkB[2][4];
#pragma unroll
    for (int mt = 0; mt < 2; ++mt)
#pragma unroll
      for (int g2 = 0; g2 < 4; ++g2) {
        pkA[mt][g2] = pkrtz(s[mt][4 * g2 + 0], s[mt][4 * g2 + 1]);
        pkB[mt][g2] = pkrtz(s[mt][4 * g2 + 2], s[mt][4 * g2 + 3]);
      }

    // ---- PV (swapped): oa[md] += V^T * P ; V from LDS ----
    __builtin_amdgcn_s_setprio(1);
#pragma unroll
    for (int kk = 0; kk < 4; ++kk) {
      const int e = kk & 1, mt = kk >> 1;
      u32 crossA = __shfl_xor(h ? pkA[mt][2 * e] : pkA[mt][2 * e + 1], 32);
      u32 crossB = __shfl_xor(h ? pkB[mt][2 * e] : pkB[mt][2 * e + 1], 32);
      union { u32 u[4]; f16x8 v; } pb;
      pb.u[0] = h ? crossA : pkA[mt][2 * e];
      pb.u[1] = h ? crossB : pkB[mt][2 * e];
      pb.u[2] = h ? pkA[mt][2 * e + 1] : crossA;
      pb.u[3] = h ? pkB[mt][2 * e + 1] : crossB;
#pragma unroll
      for (int md = 0; md < 2; ++md) {
        f16x8 vf = *(const f16x8*)(vd + paddr(md * 32 + q, kk * 16 + h * 8));
        oa[md] = __builtin_amdgcn_mfma_f32_32x32x16_f16(vf, pb.v, oa[md], 0, 0, 0);
      }
    }
    __builtin_amdgcn_s_setprio(0);

    // ---- write prefetched tile into the other buffer ----
    if (pf) writeT(cur ^ 1);
    __syncthreads();
    cur ^= 1;
  }

  // ---- merge: half1 publishes unnormalized O + (m,l); half0 combines ----
  float* O1 = (float*)(smem + 32768);   // [128 rows][64 d]; overlays half1 stg
  float* ml1 = (float*)(smem + 65536);  // float2 per row
  if (half == 1) {
#pragma unroll
    for (int mt = 0; mt < 2; ++mt)
#pragma unroll
      for (int r = 0; r < 16; ++r) {
        const int d = mt * 32 + (r & 3) + 8 * (r >> 2) + 4 * h;
        O1[(hw * 32 + q) * 64 + d] = oa[mt][r];
      }
    if (h == 0)
      ((float2*)ml1)[hw * 32 + q] = make_float2(m_run, l_run);
  }
  __syncthreads();
  float w0 = 0.f, w1 = 0.f;
  if (half == 0) {
    const float2 m1 = ((const float2*)ml1)[hw * 32 + q];
    const float mm = fmaxf(m_run, m1.x);
    w0 = __builtin_amdgcn_exp2f(m_run - mm);
    w1 = __builtin_amdgcn_exp2f(m1.x - mm);
    const float inv = 1.f / (l_run * w0 + m1.y * w1);
    w0 *= inv;
    w1 *= inv;
  }
  float* Os = (float*)smem;  // [64][68] overlay, safe after the K-loop
#pragma unroll
  for (int ph = 0; ph < 2; ++ph) {
    __syncthreads();
    if (half == 0 && (hw >> 1) == ph) {
#pragma unroll
      for (int mt = 0; mt < 2; ++mt)
#pragma unroll
        for (int r = 0; r < 16; ++r) {
          const int d = mt * 32 + (r & 3) + 8 * (r >> 2) + 4 * h;
          const int gqr = hw * 32 + q;  // global q-row in tile
          Os[((hw & 1) * 32 + q) * 68 + d] = oa[mt][r] * w0 + O1[gqr * 64 + d] * w1;
        }
    }
    __syncthreads();
    {
      const int row = tid >> 3, c0 = (tid & 7) * 8;
      float* op = O + ((size_t)bh * kS + q0 + ph * 64 + row) * kD + c0;
      const float* sp = Os + row * 68 + c0;
      *(float4*)op = *(const float4*)sp;
      *(float4*)(op + 4) = *(const float4*)(sp + 4);
    }
  }
}

// ---------------- fallback (round-1 kernel) if ws is too small -------------
__device__ __forceinline__ int swz(int row, int colh) {
  return row * 64 + (colh ^ ((row & 7) << 3));
}

__global__ __launch_bounds__(256, 4) void fattn_fallback(
    const float* __restrict__ Q, const float* __restrict__ K,
    const float* __restrict__ V, const int* __restrict__ M,
    float* __restrict__ O) {
  __shared__ __align__(16) _Float16 Kl[64 * 64];
  __shared__ __align__(16) _Float16 Vtl[64 * 64];
  __shared__ __align__(16) _Float16 Pl[64 * 64];
  __shared__ float mbl[64];

  const int tid = threadIdx.x;
  const int lane = tid & 63;
  const int w = tid >> 6;
  const int lr = lane & 15;
  const int hg = lane >> 4;
  const int NQT1 = kS / 64;
  const int bh = blockIdx.x / NQT1;
  const int qt = blockIdx.x % NQT1;
  const int b = bh / kH;
  const int q0 = qt * 64;

  f16x8 aq[2];
  {
    const int row = q0 + w * 16 + lr;
    const float* qp = Q + ((size_t)bh * kS + row) * kD;
#pragma unroll
    for (int kf = 0; kf < 2; ++kf) {
      const float* p = qp + kf * 32 + hg * 8;
      float4 x = *(const float4*)(p);
      float4 y = *(const float4*)(p + 4);
      f16x8 a;
      a[0] = (_Float16)(x.x * 0.125f); a[1] = (_Float16)(x.y * 0.125f);
      a[2] = (_Float16)(x.z * 0.125f); a[3] = (_Float16)(x.w * 0.125f);
      a[4] = (_Float16)(y.x * 0.125f); a[5] = (_Float16)(y.y * 0.125f);
      a[6] = (_Float16)(y.z * 0.125f); a[7] = (_Float16)(y.w * 0.125f);
      aq[kf] = a;
    }
  }

  typedef float f32x4 __attribute__((ext_vector_type(4)));
  f32x4 oacc[4];
#pragma unroll
  for (int c = 0; c < 4; ++c) { oacc[c][0]=0.f; oacc[c][1]=0.f; oacc[c][2]=0.f; oacc[c][3]=0.f; }
  float m_run[4], l_run[4];
#pragma unroll
  for (int r = 0; r < 4; ++r) { m_run[r] = -1e30f; l_run[r] = 0.f; }

  const float* kb = K + (size_t)bh * kS * kD;
  const float* vb = V + (size_t)bh * kS * kD;
  const int* mbp = M + b * kS;

  for (int t0 = 0; t0 < kS; t0 += 64) {
    __syncthreads();
#pragma unroll
    for (int i = 0; i < 4; ++i) {
      const int off = (tid + 256 * i) * 4;
      const int row = off >> 6;
      const int col = off & 63;
      float4 kx = *(const float4*)(kb + (size_t)(t0 + row) * kD + col);
      f16x4 hk;
      hk[0] = (_Float16)kx.x; hk[1] = (_Float16)kx.y;
      hk[2] = (_Float16)kx.z; hk[3] = (_Float16)kx.w;
      *(f16x4*)(Kl + swz(row, col)) = hk;
      float4 vx = *(const float4*)(vb + (size_t)(t0 + row) * kD + col);
      Vtl[swz(col + 0, row)] = (_Float16)vx.x;
      Vtl[swz(col + 1, row)] = (_Float16)vx.y;
      Vtl[swz(col + 2, row)] = (_Float16)vx.z;
      Vtl[swz(col + 3, row)] = (_Float16)vx.w;
    }
    if (tid < 64) mbl[tid] = mbp[t0 + tid] ? 0.f : -1e30f;
    __syncthreads();

    f32x4 s[4];
#pragma unroll
    for (int c = 0; c < 4; ++c) {
      f32x4 z; z[0]=0.f; z[1]=0.f; z[2]=0.f; z[3]=0.f;
#pragma unroll
      for (int kf = 0; kf < 2; ++kf) {
        f16x8 bk = *(const f16x8*)(Kl + swz(c * 16 + lr, kf * 32 + hg * 8));
        z = __builtin_amdgcn_mfma_f32_16x16x32_f16(aq[kf], bk, z, 0, 0, 0);
      }
      const float mval = mbl[c * 16 + lr];
#pragma unroll
      for (int r = 0; r < 4; ++r) z[r] += mval;
      s[c] = z;
    }

    float tmax[4];
#pragma unroll
    for (int r = 0; r < 4; ++r)
      tmax[r] = fmaxf(fmaxf(s[0][r], s[1][r]), fmaxf(s[2][r], s[3][r]));
#pragma unroll
    for (int off = 1; off < 16; off <<= 1)
#pragma unroll
      for (int r = 0; r < 4; ++r) tmax[r] = fmaxf(tmax[r], __shfl_xor(tmax[r], off));

    float mnew[4], corr[4], tsum[4];
#pragma unroll
    for (int r = 0; r < 4; ++r) {
      mnew[r] = fmaxf(m_run[r], tmax[r]);
      corr[r] = __expf(m_run[r] - mnew[r]);
      m_run[r] = mnew[r];
      tsum[r] = 0.f;
    }
#pragma unroll
    for (int c = 0; c < 4; ++c)
#pragma unroll
      for (int r = 0; r < 4; ++r) {
        const float p = __expf(s[c][r] - mnew[r]);
        tsum[r] += p;
        Pl[swz(w * 16 + hg * 4 + r, c * 16 + lr)] = (_Float16)p;
      }
#pragma unroll
    for (int off = 1; off < 16; off <<= 1)
#pragma unroll
      for (int r = 0; r < 4; ++r) tsum[r] += __shfl_xor(tsum[r], off);
#pragma unroll
    for (int r = 0; r < 4; ++r) l_run[r] = l_run[r] * corr[r] + tsum[r];
#pragma unroll
    for (int c = 0; c < 4; ++c)
#pragma unroll
      for (int r = 0; r < 4; ++r) oacc[c][r] *= corr[r];

#pragma unroll
    for (int kf = 0; kf < 2; ++kf) {
      f16x8 pa = *(const f16x8*)(Pl + swz(w * 16 + lr, kf * 32 + hg * 8));
#pragma unroll
      for (int cd = 0; cd < 4; ++cd) {
        f16x8 vbf = *(const f16x8*)(Vtl + swz(cd * 16 + lr, kf * 32 + hg * 8));
        oacc[cd] = __builtin_amdgcn_mfma_f32_16x16x32_f16(pa, vbf, oacc[cd], 0, 0, 0);
      }
    }
  }

#pragma unroll
  for (int r = 0; r < 4; ++r) {
    const float inv = 1.f / l_run[r];
    const int row = q0 + w * 16 + hg * 4 + r;
    float* op = O + ((size_t)bh * kS + row) * kD;
#pragma unroll
    for (int cd = 0; cd < 4; ++cd) op[cd * 16 + lr] = oacc[cd][r] * inv;
  }
}
}  // namespace

extern "C" void kernel_launch(void* const* d_in, const int* in_sizes, int n_in,
                              void* d_out, int out_size, void* d_ws, size_t ws_size,
                              hipStream_t stream) {
  (void)in_sizes; (void)n_in; (void)out_size;
  const float* q = (const float*)d_in[0];
  const float* k = (const float*)d_in[1];
  const float* v = (const float*)d_in[2];
  const int* m = (const int*)d_in[3];
  float* o = (float*)d_out;

  const size_t elems = (size_t)kBH * kS * kD;  // 4.19M
  const size_t need = 2 * elems * sizeof(_Float16)    // Kc + Vtc
                    + (size_t)kB * kS * sizeof(int)   // Idx
                    + 512;                            // NTarr + Nvarr

  if (ws_size >= need) {
    _Float16* Kc = (_Float16*)d_ws;
    _Float16* Vtc = Kc + elems;
    int* Idx = (int*)(Vtc + elems);
    int* NTarr = Idx + (size_t)kB * kS;
    int* Nvarr = NTarr + 64;
    hipLaunchKernelGGL(scan_kernel, dim3(kB), dim3(256), 0, stream, m, Idx, NTarr, Nvarr);
    hipLaunchKernelGGL(gather_kv_kernel, dim3(kBH * (kS / 64)), dim3(256), 0, stream,
                       k, v, Idx, NTarr, Kc, Vtc);
    hipLaunchKernelGGL(fattn8, dim3(kBH * NQT), dim3(512), 0, stream,
                       Kc, Vtc, q, NTarr, Nvarr, o);
  } else {
    hipLaunchKernelGGL(fattn_fallback, dim3(kBH * (kS / 64)), dim3(256), 0, stream,
                       q, k, v, m, o);
  }
}

// Round 15
// 52.032 us; speedup vs baseline: 1.9901x; 1.1203x over previous
//
#include <hip/hip_runtime.h>
#include <hip/hip_fp16.h>

namespace {
constexpr int kB = 2, kH = 16, kS = 2048, kD = 64, kBH = kB * kH;
constexpr int BQ = 128;
constexpr int NQT = kS / BQ;   // 16

typedef _Float16 f16x8 __attribute__((ext_vector_type(8)));
typedef _Float16 f16x4 __attribute__((ext_vector_type(4)));
typedef __fp16 fp16x2 __attribute__((ext_vector_type(2)));
typedef float f32x16 __attribute__((ext_vector_type(16)));
typedef unsigned int u32;

// Q prescale: 1/sqrt(64) * log2(e) -> softmax done in exp2 domain.
constexpr float kQScale = 0.125f * 1.4426950408889634f;

// Packed LDS tile: 64 logical rows x 64 f16 -> 32 prows x 128 halfwords.
__device__ __forceinline__ int paddr(int row, int col) {
  const int prow = row >> 1;
  return prow * 128 + ((((row & 1) << 6) | col) ^ ((prow & 15) << 3));
}

__device__ __forceinline__ u32 pkrtz(float a, float b) {
  union { fp16x2 h; u32 u; } c;
  c.h = __builtin_amdgcn_cvt_pkrtz(a, b);
  return c.u;
}

// ---- preprocess 1: per-batch mask scan -> compaction index + NT(even) + Nv
__global__ __launch_bounds__(256) void scan_kernel(const int* __restrict__ M,
                                                   int* __restrict__ Idx,
                                                   int* __restrict__ NTarr,
                                                   int* __restrict__ Nvarr) {
  const int b = blockIdx.x;
  const int tid = threadIdx.x;
  __shared__ int part[256];
  __shared__ int nvs;
  int m[8], sum = 0;
#pragma unroll
  for (int i = 0; i < 8; ++i) {
    m[i] = M[b * kS + tid * 8 + i];
    sum += m[i] ? 1 : 0;
  }
  part[tid] = sum;
  __syncthreads();
  for (int off = 1; off < 256; off <<= 1) {
    int v = (tid >= off) ? part[tid - off] : 0;
    __syncthreads();
    part[tid] += v;
    __syncthreads();
  }
  int run = part[tid] - sum;  // exclusive prefix
#pragma unroll
  for (int i = 0; i < 8; ++i)
    if (m[i]) Idx[b * kS + run++] = tid * 8 + i;
  if (tid == 255) nvs = part[255];
  __syncthreads();
  const int Nv = nvs;
  int NT = (Nv + 63) >> 6;
  if (NT == 0) NT = 1;
  NT += (NT & 1);  // even: main kernel processes tile PAIRS (<=32)
  const int pad = NT * 64;
  for (int j = Nv + tid; j < pad; j += 256) Idx[b * kS + j] = 0;
  if (tid == 0) { NTarr[b] = NT; Nvarr[b] = Nv; }
}

// ---- preprocess 2 (fused): gather K -> f16 [bh][j][d] and V -> f16^T
// [bh][d][j], one block per (bh, key-tile). ----
__global__ __launch_bounds__(256) void gather_kv_kernel(
    const float* __restrict__ K, const float* __restrict__ V,
    const int* __restrict__ Idx, const int* __restrict__ NTarr,
    _Float16* __restrict__ Kc, _Float16* __restrict__ Vtc) {
  __shared__ _Float16 Vl[64 * 68];
  __shared__ int ridx[64];
  const int tid = threadIdx.x;
  const int bh = blockIdx.x >> 5;
  const int jt = blockIdx.x & 31;
  const int b = bh >> 4;
  if (jt >= NTarr[b]) return;
  if (tid < 64) ridx[tid] = Idx[b * kS + jt * 64 + tid];
  __syncthreads();

  const float* kbase = K + (size_t)bh * kS * kD;
  _Float16* kout = Kc + ((size_t)bh * kS + jt * 64) * kD;
#pragma unroll
  for (int it = 0; it < 2; ++it) {
    const int e = tid + 256 * it;
    const int row = e >> 3, d0 = (e & 7) * 8;
    const float* p = kbase + (size_t)ridx[row] * kD + d0;
    float4 x = *(const float4*)p;
    float4 y = *(const float4*)(p + 4);
    f16x8 o;
    o[0] = (_Float16)x.x; o[1] = (_Float16)x.y; o[2] = (_Float16)x.z; o[3] = (_Float16)x.w;
    o[4] = (_Float16)y.x; o[5] = (_Float16)y.y; o[6] = (_Float16)y.z; o[7] = (_Float16)y.w;
    *(f16x8*)(kout + (size_t)row * kD + d0) = o;
  }

  const float* vb = V + (size_t)bh * kS * kD;
#pragma unroll
  for (int i = 0; i < 4; ++i) {
    int off = (tid + 256 * i) * 4;
    int r = off >> 6, c = off & 63;
    float4 x = *(const float4*)(vb + (size_t)ridx[r] * kD + c);
    Vl[(c + 0) * 68 + r] = (_Float16)x.x;
    Vl[(c + 1) * 68 + r] = (_Float16)x.y;
    Vl[(c + 2) * 68 + r] = (_Float16)x.z;
    Vl[(c + 3) * 68 + r] = (_Float16)x.w;
  }
  __syncthreads();
  const int d = tid >> 2, c0 = (tid & 3) * 16;
  _Float16* op = Vtc + ((size_t)bh * kD + d) * kS + jt * 64 + c0;
#pragma unroll
  for (int j = 0; j < 4; ++j)
    *(f16x4*)(op + 4 * j) = *(const f16x4*)(Vl + d * 68 + c0 + 4 * j);
}

// ------- main: R12 structure with BKV=128 (two key-subtiles / iteration).
// 4 independent QK MFMA chains (s[0..3]), one barrier per 128 keys,
// double-buffered 64KB LDS (2 blocks/CU). Compacted keys; pad-mask VALU.
__global__ __launch_bounds__(256, 2) void fattn_c(
    const _Float16* __restrict__ Kc, const _Float16* __restrict__ Vtc,
    const float* __restrict__ Q, const int* __restrict__ NTarr,
    const int* __restrict__ Nvarr, float* __restrict__ O) {
  // Kl [2buf][2sub][4096] f16 = 32KB | Vl same = 32KB. Os overlays front.
  __shared__ __align__(16) char smem[65536];
  _Float16* Kl = (_Float16*)smem;
  _Float16* Vl = (_Float16*)(smem + 32768);
  float* Os = (float*)smem;  // [64][68] epilogue overlay

  const int tid = threadIdx.x;
  const int lane = tid & 63;
  const int w = tid >> 6;    // wave 0..3
  const int q = lane & 31;   // qrow within wave tile
  const int h = lane >> 5;   // half 0/1

  // XCD-aware bijective swizzle (gridDim = 512, %8 == 0).
  const int bid = blockIdx.x;
  const int cpx = gridDim.x >> 3;
  const int sbid = (bid & 7) * cpx + (bid >> 3);
  const int bh = sbid >> 4;
  const int qt = sbid & 15;
  const int q0 = qt * BQ;
  const int b = bh >> 4;  // H=16
  const int NT = NTarr[b];   // even
  const int Nv = Nvarr[b];
  const int NP = NT >> 1;    // pairs

  // Q fragments (B-operand), pre-scaled into exp2 domain.
  f16x8 qf[4];
  {
    const float* qp = Q + ((size_t)bh * kS + q0 + w * 32 + q) * kD;
#pragma unroll
    for (int dc = 0; dc < 4; ++dc) {
      const float* p = qp + dc * 16 + h * 8;
      float4 x = *(const float4*)p;
      float4 y = *(const float4*)(p + 4);
      f16x8 a;
      a[0] = (_Float16)(x.x * kQScale); a[1] = (_Float16)(x.y * kQScale);
      a[2] = (_Float16)(x.z * kQScale); a[3] = (_Float16)(x.w * kQScale);
      a[4] = (_Float16)(y.x * kQScale); a[5] = (_Float16)(y.y * kQScale);
      a[6] = (_Float16)(y.z * kQScale); a[7] = (_Float16)(y.w * kQScale);
      qf[dc] = a;
    }
  }

  f32x16 oa[2];
#pragma unroll
  for (int i = 0; i < 16; ++i) { oa[0][i] = 0.f; oa[1][i] = 0.f; }
  float m_run = -30.f, l_run = 0.f;

  const _Float16* kb = Kc + (size_t)bh * kS * kD;
  const _Float16* vb = Vtc + (size_t)bh * kD * kS;

  // staging geometry: thread -> (row = tid>>2, colbase = (tid&3)*16)
  const int sr = tid >> 2, sc = (tid & 3) * 16;
  const int a0 = paddr(sr, sc), a1 = paddr(sr, sc + 8);

  f16x8 nk0, nk1, nv0, nv1;
  auto loadT = [&](int g) {  // g = global 64-key tile index
    const _Float16* kp = kb + (size_t)(g * 64 + sr) * kD + sc;
    const _Float16* vp = vb + (size_t)sr * kS + g * 64 + sc;
    nk0 = *(const f16x8*)(kp);
    nk1 = *(const f16x8*)(kp + 8);
    nv0 = *(const f16x8*)(vp);
    nv1 = *(const f16x8*)(vp + 8);
  };
  auto writeT = [&](int buf, int sub) {
    _Float16* kd = Kl + buf * 8192 + sub * 4096;
    _Float16* vd = Vl + buf * 8192 + sub * 4096;
    *(f16x8*)(kd + a0) = nk0; *(f16x8*)(kd + a1) = nk1;
    *(f16x8*)(vd + a0) = nv0; *(f16x8*)(vd + a1) = nv1;
  };

  // prologue: stage pair 0 into buf 0
  loadT(0); writeT(0, 0);
  loadT(1); writeT(0, 1);
  __syncthreads();

  int cur = 0;
  for (int i = 0; i < NP; ++i) {
    const bool pf = (i + 1 < NP);
    if (pf) loadT(2 * i + 2);  // T14: sub0 of next pair, in flight over QK

    const _Float16* kd = Kl + cur * 8192;
    const _Float16* vd = Vl + cur * 8192;

    // ---- QK^T (swapped), zero C-init; 4 independent chains ----
    // s[sub*2+mt][r]: key = i*128 + sub*64 + mt*32 + 8*(r>>2) + 4*h + (r&3)
    f32x16 s[4];
    __builtin_amdgcn_s_setprio(1);
#pragma unroll
    for (int sub = 0; sub < 2; ++sub)
#pragma unroll
      for (int mt = 0; mt < 2; ++mt) {
        f32x16 z;
#pragma unroll
        for (int i2 = 0; i2 < 16; ++i2) z[i2] = 0.f;
#pragma unroll
        for (int dc = 0; dc < 4; ++dc) {
          f16x8 kf = *(const f16x8*)(kd + sub * 4096 +
                                     paddr(mt * 32 + q, dc * 16 + h * 8));
          z = __builtin_amdgcn_mfma_f32_32x32x16_f16(kf, qf[dc], z, 0, 0, 0);
        }
        s[sub * 2 + mt] = z;
      }
    __builtin_amdgcn_s_setprio(0);

    if (pf) writeT(cur ^ 1, 0);  // stage sub0 while softmax runs
    if (pf) loadT(2 * i + 3);    // sub1 of next pair, in flight over softmax

    // ---- pad-mask (only tiles overlapping [Nv,...)): pure VALU ----
    if ((i + 1) * 128 > Nv) {
#pragma unroll
      for (int sub = 0; sub < 2; ++sub) {
        const int kbase = i * 128 + sub * 64 + 4 * h;
#pragma unroll
        for (int mt = 0; mt < 2; ++mt)
#pragma unroll
          for (int r = 0; r < 16; ++r) {
            const int key = kbase + mt * 32 + 8 * (r >> 2) + (r & 3);
            if (key >= Nv) s[sub * 2 + mt][r] = -1e30f;
          }
      }
    }

    // ---- tile max over 128 keys (tree) + cross-half combine ----
    float tm[16];
#pragma unroll
    for (int i2 = 0; i2 < 16; ++i2)
      tm[i2] = fmaxf(fmaxf(s[0][i2], s[1][i2]), fmaxf(s[2][i2], s[3][i2]));
#pragma unroll
    for (int st = 8; st > 0; st >>= 1)
#pragma unroll
      for (int i2 = 0; i2 < st; ++i2) tm[i2] = fmaxf(tm[i2], tm[i2 + st]);
    const float mx = fmaxf(tm[0], __shfl_xor(tm[0], 32));

    // ---- defer-max (T13) ----
    if (__any(mx > m_run + 8.f)) {
      const float mnew = fmaxf(m_run, mx);
      const float corr = __builtin_amdgcn_exp2f(m_run - mnew);
      m_run = mnew;
      l_run *= corr;
#pragma unroll
      for (int mt = 0; mt < 2; ++mt)
#pragma unroll
        for (int r = 0; r < 16; ++r) oa[mt][r] *= corr;
    }
    const float negm = -m_run;

    // ---- p = exp2(s - m); tree sum over 128 keys ----
#pragma unroll
    for (int st4 = 0; st4 < 4; ++st4)
#pragma unroll
      for (int r = 0; r < 16; ++r)
        s[st4][r] = __builtin_amdgcn_exp2f(s[st4][r] + negm);
    float tsum[16];
#pragma unroll
    for (int i2 = 0; i2 < 16; ++i2)
      tsum[i2] = (s[0][i2] + s[1][i2]) + (s[2][i2] + s[3][i2]);
#pragma unroll
    for (int st = 8; st > 0; st >>= 1)
#pragma unroll
      for (int i2 = 0; i2 < st; ++i2) tsum[i2] += tsum[i2 + st];
    l_run += tsum[0] + __shfl_xor(tsum[0], 32);

    // ---- pack P to f16 pairs ----
    u32 pkA[4][4], pkB[4][4];
#pragma unroll
    for (int st4 = 0; st4 < 4; ++st4)
#pragma unroll
      for (int g2 = 0; g2 < 4; ++g2) {
        pkA[st4][g2] = pkrtz(s[st4][4 * g2 + 0], s[st4][4 * g2 + 1]);
        pkB[st4][g2] = pkrtz(s[st4][4 * g2 + 2], s[st4][4 * g2 + 3]);
      }

    // ---- PV (swapped) over 128 keys: oa[md] += V^T * P ----
    __builtin_amdgcn_s_setprio(1);
#pragma unroll
    for (int vkk = 0; vkk < 8; ++vkk) {
      const int sub = vkk >> 2, kk = vkk & 3;
      const int e = kk & 1, mt = kk >> 1;
      const int st4 = sub * 2 + mt;
      u32 crossA = __shfl_xor(h ? pkA[st4][2 * e] : pkA[st4][2 * e + 1], 32);
      u32 crossB = __shfl_xor(h ? pkB[st4][2 * e] : pkB[st4][2 * e + 1], 32);
      union { u32 u[4]; f16x8 v; } pb;
      pb.u[0] = h ? crossA : pkA[st4][2 * e];
      pb.u[1] = h ? crossB : pkB[st4][2 * e];
      pb.u[2] = h ? pkA[st4][2 * e + 1] : crossA;
      pb.u[3] = h ? pkB[st4][2 * e + 1] : crossB;
#pragma unroll
      for (int md = 0; md < 2; ++md) {
        f16x8 vf = *(const f16x8*)(vd + sub * 4096 +
                                   paddr(md * 32 + q, kk * 16 + h * 8));
        oa[md] = __builtin_amdgcn_mfma_f32_32x32x16_f16(vf, pb.v, oa[md], 0, 0, 0);
      }
    }
    __builtin_amdgcn_s_setprio(0);

    // ---- stage sub1 of next pair ----
    if (pf) writeT(cur ^ 1, 1);
    __syncthreads();
    cur ^= 1;
  }

  // ---- epilogue: normalize, transpose via LDS, coalesced store ----
  const float inv = 1.f / l_run;
#pragma unroll
  for (int ph = 0; ph < 2; ++ph) {
    __syncthreads();
    if ((w >> 1) == ph) {
#pragma unroll
      for (int mt = 0; mt < 2; ++mt)
#pragma unroll
        for (int r = 0; r < 16; ++r) {
          int d = mt * 32 + (r & 3) + 8 * (r >> 2) + 4 * h;
          Os[((w & 1) * 32 + q) * 68 + d] = oa[mt][r] * inv;
        }
    }
    __syncthreads();
    {
      const int row = tid >> 2, cb = (tid & 3) * 16;
      float* op = O + ((size_t)bh * kS + q0 + ph * 64 + row) * kD + cb;
      const float* sp = Os + row * 68 + cb;
#pragma unroll
      for (int j = 0; j < 4; ++j) *(float4*)(op + 4 * j) = *(const float4*)(sp + 4 * j);
    }
  }
}

// ---------------- fallback (round-1 kernel) if ws is too small -------------
__device__ __forceinline__ int swz(int row, int colh) {
  return row * 64 + (colh ^ ((row & 7) << 3));
}

__global__ __launch_bounds__(256, 4) void fattn_fallback(
    const float* __restrict__ Q, const float* __restrict__ K,
    const float* __restrict__ V, const int* __restrict__ M,
    float* __restrict__ O) {
  __shared__ __align__(16) _Float16 Kl[64 * 64];
  __shared__ __align__(16) _Float16 Vtl[64 * 64];
  __shared__ __align__(16) _Float16 Pl[64 * 64];
  __shared__ float mbl[64];

  const int tid = threadIdx.x;
  const int lane = tid & 63;
  const int w = tid >> 6;
  const int lr = lane & 15;
  const int hg = lane >> 4;
  const int NQT1 = kS / 64;
  const int bh = blockIdx.x / NQT1;
  const int qt = blockIdx.x % NQT1;
  const int b = bh / kH;
  const int q0 = qt * 64;

  f16x8 aq[2];
  {
    const int row = q0 + w * 16 + lr;
    const float* qp = Q + ((size_t)bh * kS + row) * kD;
#pragma unroll
    for (int kf = 0; kf < 2; ++kf) {
      const float* p = qp + kf * 32 + hg * 8;
      float4 x = *(const float4*)(p);
      float4 y = *(const float4*)(p + 4);
      f16x8 a;
      a[0] = (_Float16)(x.x * 0.125f); a[1] = (_Float16)(x.y * 0.125f);
      a[2] = (_Float16)(x.z * 0.125f); a[3] = (_Float16)(x.w * 0.125f);
      a[4] = (_Float16)(y.x * 0.125f); a[5] = (_Float16)(y.y * 0.125f);
      a[6] = (_Float16)(y.z * 0.125f); a[7] = (_Float16)(y.w * 0.125f);
      aq[kf] = a;
    }
  }

  typedef float f32x4 __attribute__((ext_vector_type(4)));
  f32x4 oacc[4];
#pragma unroll
  for (int c = 0; c < 4; ++c) { oacc[c][0]=0.f; oacc[c][1]=0.f; oacc[c][2]=0.f; oacc[c][3]=0.f; }
  float m_run[4], l_run[4];
#pragma unroll
  for (int r = 0; r < 4; ++r) { m_run[r] = -1e30f; l_run[r] = 0.f; }

  const float* kb = K + (size_t)bh * kS * kD;
  const float* vb = V + (size_t)bh * kS * kD;
  const int* mbp = M + b * kS;

  for (int t0 = 0; t0 < kS; t0 += 64) {
    __syncthreads();
#pragma unroll
    for (int i = 0; i < 4; ++i) {
      const int off = (tid + 256 * i) * 4;
      const int row = off >> 6;
      const int col = off & 63;
      float4 kx = *(const float4*)(kb + (size_t)(t0 + row) * kD + col);
      f16x4 hk;
      hk[0] = (_Float16)kx.x; hk[1] = (_Float16)kx.y;
      hk[2] = (_Float16)kx.z; hk[3] = (_Float16)kx.w;
      *(f16x4*)(Kl + swz(row, col)) = hk;
      float4 vx = *(const float4*)(vb + (size_t)(t0 + row) * kD + col);
      Vtl[swz(col + 0, row)] = (_Float16)vx.x;
      Vtl[swz(col + 1, row)] = (_Float16)vx.y;
      Vtl[swz(col + 2, row)] = (_Float16)vx.z;
      Vtl[swz(col + 3, row)] = (_Float16)vx.w;
    }
    if (tid < 64) mbl[tid] = mbp[t0 + tid] ? 0.f : -1e30f;
    __syncthreads();

    f32x4 s[4];
#pragma unroll
    for (int c = 0; c < 4; ++c) {
      f32x4 z; z[0]=0.f; z[1]=0.f; z[2]=0.f; z[3]=0.f;
#pragma unroll
      for (int kf = 0; kf < 2; ++kf) {
        f16x8 bk = *(const f16x8*)(Kl + swz(c * 16 + lr, kf * 32 + hg * 8));
        z = __builtin_amdgcn_mfma_f32_16x16x32_f16(aq[kf], bk, z, 0, 0, 0);
      }
      const float mval = mbl[c * 16 + lr];
#pragma unroll
      for (int r = 0; r < 4; ++r) z[r] += mval;
      s[c] = z;
    }

    float tmax[4];
#pragma unroll
    for (int r = 0; r < 4; ++r)
      tmax[r] = fmaxf(fmaxf(s[0][r], s[1][r]), fmaxf(s[2][r], s[3][r]));
#pragma unroll
    for (int off = 1; off < 16; off <<= 1)
#pragma unroll
      for (int r = 0; r < 4; ++r) tmax[r] = fmaxf(tmax[r], __shfl_xor(tmax[r], off));

    float mnew[4], corr[4], tsum[4];
#pragma unroll
    for (int r = 0; r < 4; ++r) {
      mnew[r] = fmaxf(m_run[r], tmax[r]);
      corr[r] = __expf(m_run[r] - mnew[r]);
      m_run[r] = mnew[r];
      tsum[r] = 0.f;
    }
#pragma unroll
    for (int c = 0; c < 4; ++c)
#pragma unroll
      for (int r = 0; r < 4; ++r) {
        const float p = __expf(s[c][r] - mnew[r]);
        tsum[r] += p;
        Pl[swz(w * 16 + hg * 4 + r, c * 16 + lr)] = (_Float16)p;
      }
#pragma unroll
    for (int off = 1; off < 16; off <<= 1)
#pragma unroll
      for (int r = 0; r < 4; ++r) tsum[r] += __shfl_xor(tsum[r], off);
#pragma unroll
    for (int r = 0; r < 4; ++r) l_run[r] = l_run[r] * corr[r] + tsum[r];
#pragma unroll
    for (int c = 0; c < 4; ++c)
#pragma unroll
      for (int r = 0; r < 4; ++r) oacc[c][r] *= corr[r];

#pragma unroll
    for (int kf = 0; kf < 2; ++kf) {
      f16x8 pa = *(const f16x8*)(Pl + swz(w * 16 + lr, kf * 32 + hg * 8));
#pragma unroll
      for (int cd = 0; cd < 4; ++cd) {
        f16x8 vbf = *(const f16x8*)(Vtl + swz(cd * 16 + lr, kf * 32 + hg * 8));
        oacc[cd] = __builtin_amdgcn_mfma_f32_16x16x32_f16(pa, vbf, oacc[cd], 0, 0, 0);
      }
    }
  }

#pragma unroll
  for (int r = 0; r < 4; ++r) {
    const float inv = 1.f / l_run[r];
    const int row = q0 + w * 16 + hg * 4 + r;
    float* op = O + ((size_t)bh * kS + row) * kD;
#pragma unroll
    for (int cd = 0; cd < 4; ++cd) op[cd * 16 + lr] = oacc[cd][r] * inv;
  }
}
}  // namespace

extern "C" void kernel_launch(void* const* d_in, const int* in_sizes, int n_in,
                              void* d_out, int out_size, void* d_ws, size_t ws_size,
                              hipStream_t stream) {
  (void)in_sizes; (void)n_in; (void)out_size;
  const float* q = (const float*)d_in[0];
  const float* k = (const float*)d_in[1];
  const float* v = (const float*)d_in[2];
  const int* m = (const int*)d_in[3];
  float* o = (float*)d_out;

  const size_t elems = (size_t)kBH * kS * kD;  // 4.19M
  const size_t need = 2 * elems * sizeof(_Float16)    // Kc + Vtc
                    + (size_t)kB * kS * sizeof(int)   // Idx
                    + 512;                            // NTarr + Nvarr

  if (ws_size >= need) {
    _Float16* Kc = (_Float16*)d_ws;
    _Float16* Vtc = Kc + elems;
    int* Idx = (int*)(Vtc + elems);
    int* NTarr = Idx + (size_t)kB * kS;
    int* Nvarr = NTarr + 64;
    hipLaunchKernelGGL(scan_kernel, dim3(kB), dim3(256), 0, stream, m, Idx, NTarr, Nvarr);
    hipLaunchKernelGGL(gather_kv_kernel, dim3(kBH * (kS / 64)), dim3(256), 0, stream,
                       k, v, Idx, NTarr, Kc, Vtc);
    hipLaunchKernelGGL(fattn_c, dim3(kBH * NQT), dim3(256), 0, stream,
                       Kc, Vtc, q, NTarr, Nvarr, o);
  } else {
    hipLaunchKernelGGL(fattn_fallback, dim3(kBH * (kS / 64)), dim3(256), 0, stream,
                       q, k, v, m, o);
  }
}